// Round 4
// baseline (31.368 us; speedup 1.0000x reference)
//
#include <hip/hip_runtime.h>

#define BS 2048
#define DIM 256
#define MARGIN_F 0.3f
#define BM 64     // square tile edge
#define BK 64
#define PADH 8    // pad in halves; row stride 72 halves = 144 B -> balanced banks

typedef __attribute__((ext_vector_type(4))) float f32x4;
typedef __attribute__((ext_vector_type(2))) __fp16 fp16x2;   // cvt_pkrtz return type
typedef __attribute__((ext_vector_type(8))) _Float16 f16x8;  // MFMA operand type

// Kernel 1: per-row norms (exact fp32), 1 wave per row, float4 loads, shfl-only.
// Also zeroes d_out (runs stream-ordered before tl_mfma's atomics).
__global__ __launch_bounds__(256) void tl_norms(const float* __restrict__ sketch,
                                                const float* __restrict__ photo,
                                                float* __restrict__ sn,
                                                float* __restrict__ pn,
                                                float* __restrict__ pos,
                                                float* __restrict__ out) {
    const int t = threadIdx.x;
    const int w = t >> 6, lane = t & 63;
    const int row = blockIdx.x * 4 + w;
    const float4 s4 = *reinterpret_cast<const float4*>(&sketch[(size_t)row * DIM + lane * 4]);
    const float4 p4 = *reinterpret_cast<const float4*>(&photo [(size_t)row * DIM + lane * 4]);
    float vs = s4.x * s4.x + s4.y * s4.y + s4.z * s4.z + s4.w * s4.w;
    float vp = p4.x * p4.x + p4.y * p4.y + p4.z * p4.z + p4.w * p4.w;
    float dx = s4.x - p4.x, dy = s4.y - p4.y, dz = s4.z - p4.z, dw = s4.w - p4.w;
    float vd = dx * dx + dy * dy + dz * dz + dw * dw;
    #pragma unroll
    for (int off = 32; off > 0; off >>= 1) {
        vs += __shfl_down(vs, off);
        vp += __shfl_down(vp, off);
        vd += __shfl_down(vd, off);
    }
    if (lane == 0) { sn[row] = vs; pn[row] = vp; pos[row] = sqrtf(vd); }
    if (blockIdx.x == 0 && t == 0) out[0] = 0.0f;
}

// Kernel 2: MFMA cross-GEMM (fp16 in via cvt_pkrtz, fp32 acc) + fused epilogue.
// 64x64 tile / block, 4 waves, each wave 32x32 = 2x2 fragments of 16x16x32.
// grid 32x32 = 1024 blocks -> ~4 blocks/CU -> ~4 waves/SIMD of TLP.
__global__ __launch_bounds__(256) void tl_mfma(const float* __restrict__ photo,
                                               const float* __restrict__ sketch,
                                               const float* __restrict__ sn,
                                               const float* __restrict__ pn,
                                               const float* __restrict__ pos,
                                               float* __restrict__ out) {
    __shared__ _Float16 As[BM][BK + PADH];  // photo rows (i)
    __shared__ _Float16 Bs[BM][BK + PADH];  // sketch rows (j)

    const int t = threadIdx.x;
    const int i0 = blockIdx.y * BM;
    const int j0 = blockIdx.x * BM;
    const int w = t >> 6, lane = t & 63;
    const int wr = (w >> 1) * 32;   // wave row offset in tile
    const int wc = (w & 1) * 32;    // wave col offset in tile

    f32x4 acc[2][2] = {};

    const int sr = t >> 2;          // staging row 0..63 (one row per 4 threads)
    const int sc = (t & 3) * 16;    // staging col (16 floats = 64 B per thread)

    union U { fp16x2 h2[4]; f16x8 h8; };

    for (int k0 = 0; k0 < DIM; k0 += BK) {
        // ---- stage 64x64 fp32 -> fp16 for both operands (coalesced 64 B/thread)
        {
            const float4* pa = reinterpret_cast<const float4*>(&photo [(size_t)(i0 + sr) * DIM + k0 + sc]);
            const float4* pb = reinterpret_cast<const float4*>(&sketch[(size_t)(j0 + sr) * DIM + k0 + sc]);
            float4 a0 = pa[0], a1 = pa[1], a2 = pa[2], a3 = pa[3];
            float4 b0 = pb[0], b1 = pb[1], b2 = pb[2], b3 = pb[3];
            U ua, ub, uc, ud;
            ua.h2[0] = __builtin_amdgcn_cvt_pkrtz(a0.x, a0.y);
            ua.h2[1] = __builtin_amdgcn_cvt_pkrtz(a0.z, a0.w);
            ua.h2[2] = __builtin_amdgcn_cvt_pkrtz(a1.x, a1.y);
            ua.h2[3] = __builtin_amdgcn_cvt_pkrtz(a1.z, a1.w);
            uc.h2[0] = __builtin_amdgcn_cvt_pkrtz(a2.x, a2.y);
            uc.h2[1] = __builtin_amdgcn_cvt_pkrtz(a2.z, a2.w);
            uc.h2[2] = __builtin_amdgcn_cvt_pkrtz(a3.x, a3.y);
            uc.h2[3] = __builtin_amdgcn_cvt_pkrtz(a3.z, a3.w);
            ub.h2[0] = __builtin_amdgcn_cvt_pkrtz(b0.x, b0.y);
            ub.h2[1] = __builtin_amdgcn_cvt_pkrtz(b0.z, b0.w);
            ub.h2[2] = __builtin_amdgcn_cvt_pkrtz(b1.x, b1.y);
            ub.h2[3] = __builtin_amdgcn_cvt_pkrtz(b1.z, b1.w);
            ud.h2[0] = __builtin_amdgcn_cvt_pkrtz(b2.x, b2.y);
            ud.h2[1] = __builtin_amdgcn_cvt_pkrtz(b2.z, b2.w);
            ud.h2[2] = __builtin_amdgcn_cvt_pkrtz(b3.x, b3.y);
            ud.h2[3] = __builtin_amdgcn_cvt_pkrtz(b3.z, b3.w);
            *reinterpret_cast<f16x8*>(&As[sr][sc])     = ua.h8;
            *reinterpret_cast<f16x8*>(&As[sr][sc + 8]) = uc.h8;
            *reinterpret_cast<f16x8*>(&Bs[sr][sc])     = ub.h8;
            *reinterpret_cast<f16x8*>(&Bs[sr][sc + 8]) = ud.h8;
        }
        __syncthreads();
        // ---- MFMA: 2 k-slices of 32, 2x2 fragments each
        #pragma unroll
        for (int ks = 0; ks < BK / 32; ++ks) {
            const int kk = ks * 32 + (lane >> 4) * 8;
            f16x8 af[2], bf[2];
            #pragma unroll
            for (int m = 0; m < 2; ++m)
                af[m] = *reinterpret_cast<const f16x8*>(&As[wr + m * 16 + (lane & 15)][kk]);
            #pragma unroll
            for (int n = 0; n < 2; ++n)
                bf[n] = *reinterpret_cast<const f16x8*>(&Bs[wc + n * 16 + (lane & 15)][kk]);
            #pragma unroll
            for (int m = 0; m < 2; ++m)
                #pragma unroll
                for (int n = 0; n < 2; ++n)
                    acc[m][n] = __builtin_amdgcn_mfma_f32_16x16x32_f16(af[m], bf[n], acc[m][n], 0, 0, 0);
        }
        __syncthreads();
    }

    // Fused epilogue. C/D layout: col = lane&15 (j), row = (lane>>4)*4 + reg (i).
    const int jl = lane & 15;
    const int rl = (lane >> 4) * 4;

    float partial = 0.0f;
    #pragma unroll
    for (int n = 0; n < 2; ++n) {
        const int j = j0 + wc + n * 16 + jl;
        const float snj = sn[j];
        const float posj = pos[j];
        #pragma unroll
        for (int m = 0; m < 2; ++m) {
            const int ibase = i0 + wr + m * 16 + rl;
            #pragma unroll
            for (int r = 0; r < 4; ++r) {
                const int i = ibase + r;
                const float c = acc[m][n][r];
                float neg2 = fmaxf(pn[i] + snj - 2.0f * c, 0.0f);
                float tl = posj - sqrtf(neg2) + MARGIN_F;
                partial += (i != j) ? fmaxf(tl, 0.0f) : 0.0f;
            }
        }
    }

    // Block reduction -> one scaled atomicAdd per block.
    #pragma unroll
    for (int off = 32; off > 0; off >>= 1) partial += __shfl_down(partial, off);
    __shared__ float lsum[4];
    if (lane == 0) lsum[w] = partial;
    __syncthreads();
    if (t == 0) {
        float s = lsum[0] + lsum[1] + lsum[2] + lsum[3];
        atomicAdd(out, s * (1.0f / ((float)BS * (float)BS)));
    }
}

extern "C" void kernel_launch(void* const* d_in, const int* in_sizes, int n_in,
                              void* d_out, int out_size, void* d_ws, size_t ws_size,
                              hipStream_t stream) {
    const float* sketch = (const float*)d_in[0];
    const float* photo  = (const float*)d_in[1];
    float* out = (float*)d_out;

    float* sn  = (float*)d_ws;        // BS floats
    float* pn  = sn + BS;             // BS floats
    float* pos = pn + BS;             // BS floats

    // tl_norms zeroes d_out (runs before tl_mfma's atomics in stream order).
    tl_norms<<<dim3(BS / 4), dim3(256), 0, stream>>>(sketch, photo, sn, pn, pos, out);

    dim3 grid(BS / BM, BS / BM);   // 32 x 32 = 1024 blocks
    tl_mfma<<<grid, dim3(256), 0, stream>>>(photo, sketch, sn, pn, pos, out);
}